// Round 2
// baseline (958.814 us; speedup 1.0000x reference)
//
#include <hip/hip_runtime.h>
#include <hip/hip_bf16.h>

// ---------------------------------------------------------------------------
// GNN encoder for MI355X — dtype-adaptive version.
// A detector kernel determines at runtime whether float inputs are f32 or
// bf16, and whether edge_index is int64 or int32; all kernels branch
// (wave-uniformly) on flags stored in ws. Heavy math = bf16 MFMA either way.
// Outputs: h[320000] | edge_index[800000] | ee[6400000] | ls[6400000],
// stored as f32 or bf16 to match the detected input dtype.
// ---------------------------------------------------------------------------

#define NN 20000
#define NE 400000

typedef unsigned short u16;
typedef unsigned int   u32;
typedef __attribute__((ext_vector_type(8))) short short8;
typedef __attribute__((ext_vector_type(4))) float f32x4;

__device__ __forceinline__ float bf2f(u16 h) {
  union { u32 u; float f; } v; v.u = ((u32)h) << 16; return v.f;
}
__device__ __forceinline__ u16 f2bf(float f) {
  union { float f; u32 u; } v; v.f = f;
  return (u16)((v.u + 0x7FFFu + ((v.u >> 16) & 1u)) >> 16);
}
__device__ __forceinline__ float ldf(const void* p, size_t i, int f32m) {
  return f32m ? ((const float*)p)[i] : bf2f(((const u16*)p)[i]);
}
__device__ __forceinline__ int ldi(const void* p, size_t i, int i64m) {
  return i64m ? (int)((const long long*)p)[i] : ((const int*)p)[i];
}
__device__ __forceinline__ void stf(void* p, size_t i, float v, int f32m) {
  if (f32m) ((float*)p)[i] = v; else ((u16*)p)[i] = f2bf(v);
}

// --- dtype detection -------------------------------------------------------
// flags[0]=1 iff float inputs are f32 (bf16-NaN/Inf bit patterns appear when
// f32 data is read as u16 halves; impossible for genuine N(0,1) bf16 data).
// flags[1]=1 iff edge_index is int64 (all odd int32 slots are high words = 0).
__global__ void k_detect(const u16* __restrict__ x16,
                         const int* __restrict__ ei32, int* __restrict__ flags) {
  __shared__ int s_f32, s_i32;
  if (threadIdx.x == 0) { s_f32 = 0; s_i32 = 0; }
  __syncthreads();
  for (int i = threadIdx.x; i < NN * 16; i += 1024) {
    u16 v = x16[i];
    if ((v & 0x7F80u) == 0x7F80u) s_f32 = 1;   // benign race, all write 1
  }
  for (int i = threadIdx.x; i < 200000; i += 1024)
    if (ei32[2 * i + 1] != 0) s_i32 = 1;
  __syncthreads();
  if (threadIdx.x == 0) { flags[0] = s_f32; flags[1] = s_i32 ? 0 : 1; }
}

// --- pack W2 [128,512] into MFMA B-fragment order -------------------------
// B-frag for (kb,ks): lane L holds W2[ks*32 + (L>>4)*8 + j][kb*16 + (L&15)]
__global__ void k_pack_w2(const void* __restrict__ W2, u16* __restrict__ w2p,
                          const int* __restrict__ flags) {
  const int f32m = flags[0];
  int t = blockIdx.x * 256 + threadIdx.x;          // 32*4*64 = 8192
  if (t >= 32 * 4 * 64) return;
  int lane = t & 63;
  int ks = (t >> 6) & 3;
  int kb = t >> 8;
  int n = lane & 15, q = lane >> 4;
  for (int j = 0; j < 8; ++j) {
    int h = ks * 32 + q * 8 + j;
    w2p[(size_t)t * 8 + j] = f2bf(ldf(W2, (size_t)h * 512 + kb * 16 + n, f32m));
  }
}

// --- pack W1 [16,128] zero-padded to K=32 into B-fragment order -----------
__global__ void k_pack_w1(const void* __restrict__ W1, u16* __restrict__ w1p,
                          const int* __restrict__ flags) {
  const int f32m = flags[0];
  int t = blockIdx.x * 256 + threadIdx.x;          // 8*64 = 512
  if (t >= 8 * 64) return;
  int lane = t & 63;
  int n = t >> 6;
  int col = n * 16 + (lane & 15), q = lane >> 4;
  for (int j = 0; j < 8; ++j) {
    int kk = q * 8 + j;
    w1p[(size_t)t * 8 + j] = (kk < 16) ? f2bf(ldf(W1, (size_t)kk * 128 + col, f32m)) : (u16)0;
  }
}

// --- node embedding: h0 = relu(x @ Wn + bn) -------------------------------
__global__ void k_embed(const void* __restrict__ x, const void* __restrict__ Wn,
                        const void* __restrict__ bn, float* __restrict__ h0,
                        const int* __restrict__ flags) {
  const int f32m = flags[0];
  int t = blockIdx.x * 256 + threadIdx.x;
  if (t >= NN * 16) return;
  int n = t >> 4, d = t & 15;
  float acc = ldf(bn, d, f32m);
  for (int k = 0; k < 16; ++k)
    acc += ldf(x, n * 16 + k, f32m) * ldf(Wn, k * 16 + d, f32m);
  h0[t] = fmaxf(acc, 0.f);
}

// --- combine: h_new = aggr + h_old @ root + bias --------------------------
__global__ void k_combine(const float* __restrict__ h_old,
                          const float* __restrict__ aggr,
                          const void* __restrict__ root,
                          const void* __restrict__ bias,
                          float* __restrict__ h_new, void* __restrict__ out,
                          const int* __restrict__ flags) {
  const int f32m = flags[0];
  int t = blockIdx.x * 256 + threadIdx.x;
  if (t >= NN * 16) return;
  int n = t >> 4, d = t & 15;
  float acc = aggr[t] + ldf(bias, d, f32m);
  for (int k = 0; k < 16; ++k)
    acc += h_old[n * 16 + k] * ldf(root, (size_t)k * 16 + d, f32m);
  if (h_new) h_new[t] = acc;
  else       stf(out, t, acc, f32m);
}

// --- fused edge kernel: per 128-edge tile ---------------------------------
__launch_bounds__(256, 2)
__global__ void k_edge(const void* __restrict__ ea, const void* __restrict__ ei,
                       const float* __restrict__ hprev,
                       const u16* __restrict__ w2p, const u16* __restrict__ w1p,
                       const void* __restrict__ b1, const void* __restrict__ b2,
                       float* __restrict__ aggr, const int* __restrict__ flags) {
  __shared__ u16   ea_lds[128 * 56];    // stride 56 u16: rows 16B-aligned
  __shared__ u16   a2_lds[128 * 136];   // stride 136: word-stride ≡ 4 mod 32
  __shared__ float nf_lds[128 * 36];
  __shared__ float msg_lds[128 * 17];
  __shared__ float b1_lds[128];
  __shared__ int   dst_lds[128];

  const int f32m = flags[0], i64m = flags[1];
  const int t = threadIdx.x;
  const int lane = t & 63, w = t >> 6;
  const int q = lane >> 4, l16 = lane & 15;

  {  // one-time: zero ea pad cols 16..31 (MFMA K-padding), stage b1
    int row = t >> 1, hh = t & 1;
    uint4 z = make_uint4(0, 0, 0, 0);
    *(uint4*)((char*)ea_lds + row * 112 + 32 + hh * 16) = z;
    if (t < 128) b1_lds[t] = ldf(b1, t, f32m);
  }

  // B fragments for GEMM2: wave w owns kb = w*8 .. w*8+7, kept in registers
  short8 B[8][4];
  {
    const short8* w2pf = (const short8*)w2p;
#pragma unroll
    for (int i = 0; i < 8; ++i)
#pragma unroll
      for (int ks = 0; ks < 4; ++ks)
        B[i][ks] = w2pf[((w * 8 + i) * 4 + ks) * 64 + lane];
  }
  float b2v[8];
#pragma unroll
  for (int i = 0; i < 8; ++i) b2v[i] = ldf(b2, (w * 8 + i) * 16 + l16, f32m);

  const short8* w1pf = (const short8*)w1p;

  for (int tile = blockIdx.x; tile < NE / 128; tile += gridDim.x) {
    const int e0 = tile * 128;
    __syncthreads();  // previous tile's epilogue done before overwriting LDS
    {  // phase 0
      int e = t >> 1, hh = t & 1;               // hh=0 -> dst, hh=1 -> src
      int node = hh ? ldi(ei, e0 + e, i64m) : ldi(ei, NE + e0 + e, i64m);
      const float4* hp = (const float4*)(hprev + (size_t)node * 16);
      float4* np_ = (float4*)(nf_lds + e * 36 + hh * 16);
      np_[0] = hp[0]; np_[1] = hp[1]; np_[2] = hp[2]; np_[3] = hp[3];
      if (!hh) dst_lds[e] = node;
      if (f32m) {
        const float4* ef = (const float4*)((const float*)ea + (size_t)(e0 + e) * 16 + hh * 8);
        float4 a0 = ef[0], a1 = ef[1];
        union { uint4 qv; u16 h[8]; } pk;
        pk.h[0] = f2bf(a0.x); pk.h[1] = f2bf(a0.y);
        pk.h[2] = f2bf(a0.z); pk.h[3] = f2bf(a0.w);
        pk.h[4] = f2bf(a1.x); pk.h[5] = f2bf(a1.y);
        pk.h[6] = f2bf(a1.z); pk.h[7] = f2bf(a1.w);
        *(uint4*)((char*)ea_lds + e * 112 + hh * 16) = pk.qv;
      } else {
        *(uint4*)((char*)ea_lds + e * 112 + hh * 16) =
            *(const uint4*)((const u16*)ea + (size_t)(e0 + e) * 16 + hh * 8);
      }
      float* mz = msg_lds + e * 17 + hh * 8;
#pragma unroll
      for (int k = 0; k < 8; ++k) mz[k] = 0.f;
    }
    __syncthreads();
    // phase 1: GEMM1 -> A2 = relu(ea@W1+b1), bf16 in LDS
#pragma unroll
    for (int mm = 0; mm < 2; ++mm) {
      int m = w * 2 + mm;
      short8 A = *(const short8*)&ea_lds[(m * 16 + l16) * 56 + q * 8];
#pragma unroll
      for (int n = 0; n < 8; ++n) {
        f32x4 c = {0.f, 0.f, 0.f, 0.f};
        c = __builtin_amdgcn_mfma_f32_16x16x32_bf16(A, w1pf[n * 64 + lane], c, 0, 0, 0);
        float bb = b1_lds[n * 16 + l16];
#pragma unroll
        for (int r = 0; r < 4; ++r)
          a2_lds[(m * 16 + q * 4 + r) * 136 + n * 16 + l16] =
              f2bf(fmaxf(c[r] + bb, 0.f));
      }
    }
    __syncthreads();
    // phase 2: chunked GEMM2 + nf contraction; waves split kb space
#pragma unroll 1
    for (int mi = 0; mi < 8; ++mi) {
      int m = (mi + w * 2) & 7;  // stagger to decorrelate LDS atomics
      const short8* ap = (const short8*)&a2_lds[(m * 16 + l16) * 136 + q * 8];
      short8 A0 = ap[0], A1 = ap[4], A2f = ap[8], A3 = ap[12];
      float mr0 = 0.f, mr1 = 0.f, mr2 = 0.f, mr3 = 0.f;
#pragma unroll
      for (int i = 0; i < 8; ++i) {
        f32x4 c = {b2v[i], b2v[i], b2v[i], b2v[i]};  // b2 rides in C-operand
        c = __builtin_amdgcn_mfma_f32_16x16x32_bf16(A0, B[i][0], c, 0, 0, 0);
        c = __builtin_amdgcn_mfma_f32_16x16x32_bf16(A1, B[i][1], c, 0, 0, 0);
        c = __builtin_amdgcn_mfma_f32_16x16x32_bf16(A2f, B[i][2], c, 0, 0, 0);
        c = __builtin_amdgcn_mfma_f32_16x16x32_bf16(A3, B[i][3], c, 0, 0, 0);
        int kb = w * 8 + i;
        const float* nfc = nf_lds + kb;
        mr0 += nfc[(m * 16 + q * 4 + 0) * 36] * c[0];
        mr1 += nfc[(m * 16 + q * 4 + 1) * 36] * c[1];
        mr2 += nfc[(m * 16 + q * 4 + 2) * 36] * c[2];
        mr3 += nfc[(m * 16 + q * 4 + 3) * 36] * c[3];
      }
      int eb = (m * 16 + q * 4) * 17 + l16;
      atomicAdd(&msg_lds[eb + 0 * 17], mr0);
      atomicAdd(&msg_lds[eb + 1 * 17], mr1);
      atomicAdd(&msg_lds[eb + 2 * 17], mr2);
      atomicAdd(&msg_lds[eb + 3 * 17], mr3);
    }
    __syncthreads();
    {  // epilogue: scatter to aggr[dst]
      int e = t >> 1, dh = t & 1;
      int dnode = dst_lds[e];
      float* ap2 = aggr + (size_t)dnode * 16 + dh * 8;
      const float* mp = msg_lds + e * 17 + dh * 8;
#pragma unroll
      for (int dd = 0; dd < 8; ++dd) atomicAdd(ap2 + dd, mp[dd]);
    }
  }
}

// --- edge embedding + log_softmax -----------------------------------------
__global__ void k_ee(const void* __restrict__ ea, const void* __restrict__ We,
                     const void* __restrict__ be, void* __restrict__ out,
                     const int* __restrict__ flags) {
  const int f32m = flags[0];
  __shared__ float W[256];
  __shared__ float Bv[16];
  int t = threadIdx.x;
  W[t] = ldf(We, t, f32m);
  if (t < 16) Bv[t] = ldf(be, t, f32m);
  __syncthreads();
  int e = blockIdx.x * 256 + t;
  if (e >= NE) return;
  float v[16];
  if (f32m) {
    const float4* ep = (const float4*)((const float*)ea + (size_t)e * 16);
    float4 r0 = ep[0], r1 = ep[1], r2 = ep[2], r3 = ep[3];
    v[0]=r0.x; v[1]=r0.y; v[2]=r0.z; v[3]=r0.w;
    v[4]=r1.x; v[5]=r1.y; v[6]=r1.z; v[7]=r1.w;
    v[8]=r2.x; v[9]=r2.y; v[10]=r2.z; v[11]=r2.w;
    v[12]=r3.x; v[13]=r3.y; v[14]=r3.z; v[15]=r3.w;
  } else {
    union { uint4 qv[2]; u16 h[16]; } rw;
    const uint4* ep = (const uint4*)((const u16*)ea + (size_t)e * 16);
    rw.qv[0] = ep[0]; rw.qv[1] = ep[1];
#pragma unroll
    for (int k = 0; k < 16; ++k) v[k] = bf2f(rw.h[k]);
  }
  float o[16];
  float mx = 0.f;
#pragma unroll
  for (int d = 0; d < 16; ++d) {
    float acc = Bv[d];
#pragma unroll
    for (int k = 0; k < 16; ++k) acc += v[k] * W[k * 16 + d];
    acc = fmaxf(acc, 0.f);
    o[d] = acc;
    mx = fmaxf(mx, acc);
  }
  float s = 0.f;
#pragma unroll
  for (int d = 0; d < 16; ++d) s += __expf(o[d] - mx);
  float lse = mx + __logf(s);
  const size_t off_ee = 1120000, off_ls = 7520000;
  if (f32m) {
    union { float4 fv; float f[4]; } pe, pl;
    float* oe = (float*)out + off_ee + (size_t)e * 16;
    float* ol = (float*)out + off_ls + (size_t)e * 16;
#pragma unroll
    for (int g = 0; g < 4; ++g) {
#pragma unroll
      for (int d = 0; d < 4; ++d) { pe.f[d] = o[g*4+d]; pl.f[d] = o[g*4+d] - lse; }
      ((float4*)oe)[g] = pe.fv;
      ((float4*)ol)[g] = pl.fv;
    }
  } else {
    union { uint4 qv[2]; u16 h[16]; } pe, pl;
#pragma unroll
    for (int d = 0; d < 16; ++d) {
      pe.h[d] = f2bf(o[d]);
      pl.h[d] = f2bf(o[d] - lse);
    }
    uint4* oe = (uint4*)((u16*)out + off_ee + (size_t)e * 16);
    uint4* ol = (uint4*)((u16*)out + off_ls + (size_t)e * 16);
    oe[0] = pe.qv[0]; oe[1] = pe.qv[1];
    ol[0] = pl.qv[0]; ol[1] = pl.qv[1];
  }
}

// --- edge_index passthrough -----------------------------------------------
__global__ void k_idx(const void* __restrict__ ei, void* __restrict__ out,
                      const int* __restrict__ flags) {
  const int f32m = flags[0], i64m = flags[1];
  int i = blockIdx.x * 256 + threadIdx.x;
  if (i >= 2 * NE) return;
  float v = i64m ? (float)((const long long*)ei)[i] : (float)((const int*)ei)[i];
  stf(out, (size_t)320000 + i, v, f32m);
}

extern "C" void kernel_launch(void* const* d_in, const int* in_sizes, int n_in,
                              void* d_out, int out_size, void* d_ws, size_t ws_size,
                              hipStream_t stream) {
  const void* x     = d_in[0];
  const void* ei    = d_in[1];
  const void* ea    = d_in[2];
  const void* Wn    = d_in[3];
  const void* bn    = d_in[4];
  const void* We    = d_in[5];
  const void* be    = d_in[6];
  const void* W1    = d_in[7];
  const void* b1    = d_in[8];
  const void* W2    = d_in[9];
  const void* b2    = d_in[10];
  const void* root1 = d_in[11];
  const void* bias1 = d_in[12];
  const void* root2 = d_in[13];
  const void* bias2 = d_in[14];

  char* ws = (char*)d_ws;
  int*   flags = (int*)ws;                              // 16 B
  float* h0   = (float*)(ws + 16);                      // 1,280,000 B
  float* h1   = (float*)(ws + 16 + 1280000);            // 1,280,000 B
  float* aggr = (float*)(ws + 16 + 2560000);            // 1,280,000 B
  u16*   w2p  = (u16*)(ws + 16 + 3840000);              //   131,072 B
  u16*   w1p  = (u16*)(ws + 16 + 3840000 + 131072);     //     8,192 B

  k_detect<<<1, 1024, 0, stream>>>((const u16*)x, (const int*)ei, flags);
  k_pack_w2<<<32, 256, 0, stream>>>(W2, w2p, flags);
  k_pack_w1<<<2, 256, 0, stream>>>(W1, w1p, flags);
  k_embed<<<1250, 256, 0, stream>>>(x, Wn, bn, h0, flags);

  hipMemsetAsync(aggr, 0, (size_t)NN * 16 * 4, stream);
  k_edge<<<512, 256, 0, stream>>>(ea, ei, h0, w2p, w1p, b1, b2, aggr, flags);
  k_combine<<<1250, 256, 0, stream>>>(h0, aggr, root1, bias1, h1, nullptr, flags);

  hipMemsetAsync(aggr, 0, (size_t)NN * 16 * 4, stream);
  k_edge<<<512, 256, 0, stream>>>(ea, ei, h1, w2p, w1p, b1, b2, aggr, flags);
  k_combine<<<1250, 256, 0, stream>>>(h1, aggr, root2, bias2, nullptr, d_out, flags);

  k_ee<<<1563, 256, 0, stream>>>(ea, We, be, d_out, flags);
  k_idx<<<3125, 256, 0, stream>>>(ei, d_out, flags);
}

// Round 3
// 646.096 us; speedup vs baseline: 1.4840x; 1.4840x over previous
//
#include <hip/hip_runtime.h>
#include <hip/hip_bf16.h>

// ---------------------------------------------------------------------------
// GNN encoder for MI355X — CSR-aggregation version.
// Round-2 profile: 74% of time in k_edge's 6.4M global f32 atomics (204 MB of
// 32B fabric RMWs per dispatch). Fix: build CSR once (800k atomics total),
// k_edge writes per-edge msg coalesced, k_gather sums per-node via CSR and
// fuses the root/bias combine. Dtype-adaptive (f32/bf16, i64/i32) as before.
// ---------------------------------------------------------------------------

#define NN 20000
#define NE 400000

typedef unsigned short u16;
typedef unsigned int   u32;
typedef __attribute__((ext_vector_type(8))) short short8;
typedef __attribute__((ext_vector_type(4))) float f32x4;

__device__ __forceinline__ float bf2f(u16 h) {
  union { u32 u; float f; } v; v.u = ((u32)h) << 16; return v.f;
}
__device__ __forceinline__ u16 f2bf(float f) {
  union { float f; u32 u; } v; v.f = f;
  return (u16)((v.u + 0x7FFFu + ((v.u >> 16) & 1u)) >> 16);
}
__device__ __forceinline__ float ldf(const void* p, size_t i, int f32m) {
  return f32m ? ((const float*)p)[i] : bf2f(((const u16*)p)[i]);
}
__device__ __forceinline__ int ldi(const void* p, size_t i, int i64m) {
  return i64m ? (int)((const long long*)p)[i] : ((const int*)p)[i];
}
__device__ __forceinline__ void stf(void* p, size_t i, float v, int f32m) {
  if (f32m) ((float*)p)[i] = v; else ((u16*)p)[i] = f2bf(v);
}

// --- dtype detection (parallel; flags pre-zeroed by memset) ----------------
// flags[0]=1 -> float inputs are f32. flags[1]=1 -> some high int32 word
// nonzero (i.e. edge_index is int32); consumers use i64m = !flags[1].
__global__ void k_detect(const u16* __restrict__ x16,
                         const int* __restrict__ ei32, int* __restrict__ flags) {
  int t = blockIdx.x * 256 + threadIdx.x;
  int found_f32 = 0, found_hi = 0;
  for (int i = t; i < NN * 16; i += 64 * 256) {
    u16 v = x16[i];
    if ((v & 0x7F80u) == 0x7F80u) found_f32 = 1;  // Inf/NaN pattern: only f32 halves
  }
  for (int i = t; i < 200000; i += 64 * 256)
    if (ei32[2 * i + 1] != 0) found_hi = 1;
  if (__any(found_f32) && (threadIdx.x & 63) == 0) atomicOr(&flags[0], 1);
  if (__any(found_hi) && (threadIdx.x & 63) == 0) atomicOr(&flags[1], 1);
}

// --- pack W2 [128,512] into MFMA B-fragment order -------------------------
__global__ void k_pack_w2(const void* __restrict__ W2, u16* __restrict__ w2p,
                          const int* __restrict__ flags) {
  const int f32m = flags[0];
  int t = blockIdx.x * 256 + threadIdx.x;          // 32*4*64 = 8192
  if (t >= 32 * 4 * 64) return;
  int lane = t & 63;
  int ks = (t >> 6) & 3;
  int kb = t >> 8;
  int n = lane & 15, q = lane >> 4;
  for (int j = 0; j < 8; ++j) {
    int h = ks * 32 + q * 8 + j;
    w2p[(size_t)t * 8 + j] = f2bf(ldf(W2, (size_t)h * 512 + kb * 16 + n, f32m));
  }
}

// --- pack W1 [16,128] zero-padded to K=32 into B-fragment order -----------
__global__ void k_pack_w1(const void* __restrict__ W1, u16* __restrict__ w1p,
                          const int* __restrict__ flags) {
  const int f32m = flags[0];
  int t = blockIdx.x * 256 + threadIdx.x;          // 8*64 = 512
  if (t >= 8 * 64) return;
  int lane = t & 63;
  int n = t >> 6;
  int col = n * 16 + (lane & 15), q = lane >> 4;
  for (int j = 0; j < 8; ++j) {
    int kk = q * 8 + j;
    w1p[(size_t)t * 8 + j] = (kk < 16) ? f2bf(ldf(W1, (size_t)kk * 128 + col, f32m)) : (u16)0;
  }
}

// --- node embedding: h0 = relu(x @ Wn + bn) -------------------------------
__global__ void k_embed(const void* __restrict__ x, const void* __restrict__ Wn,
                        const void* __restrict__ bn, float* __restrict__ h0,
                        const int* __restrict__ flags) {
  const int f32m = flags[0];
  int t = blockIdx.x * 256 + threadIdx.x;
  if (t >= NN * 16) return;
  int n = t >> 4, d = t & 15;
  float acc = ldf(bn, d, f32m);
  for (int k = 0; k < 16; ++k)
    acc += ldf(x, n * 16 + k, f32m) * ldf(Wn, k * 16 + d, f32m);
  h0[t] = fmaxf(acc, 0.f);
}

// --- CSR build -------------------------------------------------------------
__global__ void k_count(const void* __restrict__ ei, int* __restrict__ cnt,
                        const int* __restrict__ flags) {
  const int i64m = !flags[1];
  int i = blockIdx.x * 256 + threadIdx.x;
  if (i < NE) atomicAdd(&cnt[ldi(ei, NE + i, i64m)], 1);
}

__global__ void k_scan(const int* __restrict__ cnt, int* __restrict__ rowptr,
                       int* __restrict__ cursor) {
  __shared__ int part[1024];
  int t = threadIdx.x;
  int base = t * 20;                               // 1024*20 = 20480 >= NN
  int s = 0;
  for (int j = 0; j < 20; ++j) { int idx = base + j; if (idx < NN) s += cnt[idx]; }
  part[t] = s;
  __syncthreads();
  for (int off = 1; off < 1024; off <<= 1) {
    int v = (t >= off) ? part[t - off] : 0;
    __syncthreads();
    part[t] += v;
    __syncthreads();
  }
  int run = t ? part[t - 1] : 0;
  for (int j = 0; j < 20; ++j) {
    int idx = base + j;
    if (idx < NN) {
      int c = cnt[idx];                            // read BEFORE cursor aliasing write
      rowptr[idx] = run; cursor[idx] = run; run += c;
    }
  }
  if (t == 1023) rowptr[NN] = part[1023];
}

__global__ void k_scatter(const void* __restrict__ ei, int* __restrict__ cursor,
                          int* __restrict__ eidx, const int* __restrict__ flags) {
  const int i64m = !flags[1];
  int i = blockIdx.x * 256 + threadIdx.x;
  if (i >= NE) return;
  int d = ldi(ei, NE + i, i64m);
  int pos = atomicAdd(&cursor[d], 1);
  eidx[pos] = i;
}

// --- fused edge kernel: per 128-edge tile ---------------------------------
// use_csr=1: write msg[e][16] coalesced.  use_csr=0: atomic into aggr (fallback).
__launch_bounds__(256, 2)
__global__ void k_edge(const void* __restrict__ ea, const void* __restrict__ ei,
                       const float* __restrict__ hprev,
                       const u16* __restrict__ w2p, const u16* __restrict__ w1p,
                       const void* __restrict__ b1, const void* __restrict__ b2,
                       float* __restrict__ msg, float* __restrict__ aggr,
                       const int* __restrict__ flags, int use_csr) {
  __shared__ u16   ea_lds[128 * 56];    // stride 56 u16: rows 16B-aligned
  __shared__ u16   a2_lds[128 * 136];   // stride 136: word-stride ≡ 4 mod 32
  __shared__ float nf_lds[128 * 36];
  __shared__ float msg_lds[128 * 17];
  __shared__ float b1_lds[128];
  __shared__ int   dst_lds[128];

  const int f32m = flags[0], i64m = !flags[1];
  const int t = threadIdx.x;
  const int lane = t & 63, w = t >> 6;
  const int q = lane >> 4, l16 = lane & 15;

  {  // one-time: zero ea pad cols 16..31 (MFMA K-padding), stage b1
    int row = t >> 1, hh = t & 1;
    uint4 z = make_uint4(0, 0, 0, 0);
    *(uint4*)((char*)ea_lds + row * 112 + 32 + hh * 16) = z;
    if (t < 128) b1_lds[t] = ldf(b1, t, f32m);
  }

  // B fragments for GEMM2: wave w owns kb = w*8 .. w*8+7, kept in registers
  short8 B[8][4];
  {
    const short8* w2pf = (const short8*)w2p;
#pragma unroll
    for (int i = 0; i < 8; ++i)
#pragma unroll
      for (int ks = 0; ks < 4; ++ks)
        B[i][ks] = w2pf[((w * 8 + i) * 4 + ks) * 64 + lane];
  }
  float b2v[8];
#pragma unroll
  for (int i = 0; i < 8; ++i) b2v[i] = ldf(b2, (w * 8 + i) * 16 + l16, f32m);

  const short8* w1pf = (const short8*)w1p;

  for (int tile = blockIdx.x; tile < NE / 128; tile += gridDim.x) {
    const int e0 = tile * 128;
    __syncthreads();  // previous tile's epilogue done before overwriting LDS
    {  // phase 0
      int e = t >> 1, hh = t & 1;               // hh=0 -> dst, hh=1 -> src
      int node = hh ? ldi(ei, e0 + e, i64m) : ldi(ei, NE + e0 + e, i64m);
      const float4* hp = (const float4*)(hprev + (size_t)node * 16);
      float4* np_ = (float4*)(nf_lds + e * 36 + hh * 16);
      np_[0] = hp[0]; np_[1] = hp[1]; np_[2] = hp[2]; np_[3] = hp[3];
      if (!hh) dst_lds[e] = node;
      if (f32m) {
        const float4* ef = (const float4*)((const float*)ea + (size_t)(e0 + e) * 16 + hh * 8);
        float4 a0 = ef[0], a1 = ef[1];
        union { uint4 qv; u16 h[8]; } pk;
        pk.h[0] = f2bf(a0.x); pk.h[1] = f2bf(a0.y);
        pk.h[2] = f2bf(a0.z); pk.h[3] = f2bf(a0.w);
        pk.h[4] = f2bf(a1.x); pk.h[5] = f2bf(a1.y);
        pk.h[6] = f2bf(a1.z); pk.h[7] = f2bf(a1.w);
        *(uint4*)((char*)ea_lds + e * 112 + hh * 16) = pk.qv;
      } else {
        *(uint4*)((char*)ea_lds + e * 112 + hh * 16) =
            *(const uint4*)((const u16*)ea + (size_t)(e0 + e) * 16 + hh * 8);
      }
      float* mz = msg_lds + e * 17 + hh * 8;
#pragma unroll
      for (int k = 0; k < 8; ++k) mz[k] = 0.f;
    }
    __syncthreads();
    // phase 1: GEMM1 -> A2 = relu(ea@W1+b1), bf16 in LDS
#pragma unroll
    for (int mm = 0; mm < 2; ++mm) {
      int m = w * 2 + mm;
      short8 A = *(const short8*)&ea_lds[(m * 16 + l16) * 56 + q * 8];
#pragma unroll
      for (int n = 0; n < 8; ++n) {
        f32x4 c = {0.f, 0.f, 0.f, 0.f};
        c = __builtin_amdgcn_mfma_f32_16x16x32_bf16(A, w1pf[n * 64 + lane], c, 0, 0, 0);
        float bb = b1_lds[n * 16 + l16];
#pragma unroll
        for (int r = 0; r < 4; ++r)
          a2_lds[(m * 16 + q * 4 + r) * 136 + n * 16 + l16] =
              f2bf(fmaxf(c[r] + bb, 0.f));
      }
    }
    __syncthreads();
    // phase 2: chunked GEMM2 + nf contraction; waves split kb space
#pragma unroll 1
    for (int mi = 0; mi < 8; ++mi) {
      int m = (mi + w * 2) & 7;  // stagger to decorrelate LDS atomics
      const short8* ap = (const short8*)&a2_lds[(m * 16 + l16) * 136 + q * 8];
      short8 A0 = ap[0], A1 = ap[4], A2f = ap[8], A3 = ap[12];
      float mr0 = 0.f, mr1 = 0.f, mr2 = 0.f, mr3 = 0.f;
#pragma unroll
      for (int i = 0; i < 8; ++i) {
        f32x4 c = {b2v[i], b2v[i], b2v[i], b2v[i]};  // b2 rides in C-operand
        c = __builtin_amdgcn_mfma_f32_16x16x32_bf16(A0, B[i][0], c, 0, 0, 0);
        c = __builtin_amdgcn_mfma_f32_16x16x32_bf16(A1, B[i][1], c, 0, 0, 0);
        c = __builtin_amdgcn_mfma_f32_16x16x32_bf16(A2f, B[i][2], c, 0, 0, 0);
        c = __builtin_amdgcn_mfma_f32_16x16x32_bf16(A3, B[i][3], c, 0, 0, 0);
        int kb = w * 8 + i;
        const float* nfc = nf_lds + kb;
        mr0 += nfc[(m * 16 + q * 4 + 0) * 36] * c[0];
        mr1 += nfc[(m * 16 + q * 4 + 1) * 36] * c[1];
        mr2 += nfc[(m * 16 + q * 4 + 2) * 36] * c[2];
        mr3 += nfc[(m * 16 + q * 4 + 3) * 36] * c[3];
      }
      int eb = (m * 16 + q * 4) * 17 + l16;
      atomicAdd(&msg_lds[eb + 0 * 17], mr0);
      atomicAdd(&msg_lds[eb + 1 * 17], mr1);
      atomicAdd(&msg_lds[eb + 2 * 17], mr2);
      atomicAdd(&msg_lds[eb + 3 * 17], mr3);
    }
    __syncthreads();
    if (use_csr) {  // epilogue: coalesced msg write
      int e = t >> 1, dh = t & 1;
      const float* mp = msg_lds + e * 17 + dh * 8;
      float4 a = {mp[0], mp[1], mp[2], mp[3]};
      float4 b = {mp[4], mp[5], mp[6], mp[7]};
      float4* g = (float4*)(msg + (size_t)(e0 + e) * 16 + dh * 8);
      g[0] = a; g[1] = b;
    } else {        // fallback: scatter atomics to aggr[dst]
      int e = t >> 1, dh = t & 1;
      int dnode = dst_lds[e];
      float* ap2 = aggr + (size_t)dnode * 16 + dh * 8;
      const float* mp = msg_lds + e * 17 + dh * 8;
#pragma unroll
      for (int dd = 0; dd < 8; ++dd) atomicAdd(ap2 + dd, mp[dd]);
    }
  }
}

// --- gather + combine: h_new = csr_sum(msg) + h_old @ root + bias ---------
__global__ void k_gather(const float* __restrict__ msg,
                         const int* __restrict__ rowptr,
                         const int* __restrict__ eidx,
                         const float* __restrict__ h_old,
                         const void* __restrict__ root,
                         const void* __restrict__ bias,
                         float* __restrict__ h_new, void* __restrict__ out,
                         const int* __restrict__ flags) {
  const int f32m = flags[0];
  __shared__ float R[256];
  __shared__ float Bv[16];
  int tt = threadIdx.x;
  R[tt] = ldf(root, tt, f32m);
  if (tt < 16) Bv[tt] = ldf(bias, tt, f32m);
  __syncthreads();
  int t = blockIdx.x * 256 + tt;
  if (t >= NN * 16) return;
  int n = t >> 4, d = t & 15;
  float acc = Bv[d];
#pragma unroll
  for (int k = 0; k < 16; ++k) acc += h_old[n * 16 + k] * R[k * 16 + d];
  int beg = rowptr[n], end = rowptr[n + 1];
  for (int i = beg; i < end; ++i)
    acc += msg[(size_t)eidx[i] * 16 + d];
  if (h_new) h_new[t] = acc;
  else       stf(out, t, acc, f32m);
}

// --- fallback combine (non-CSR path) --------------------------------------
__global__ void k_combine(const float* __restrict__ h_old,
                          const float* __restrict__ aggr,
                          const void* __restrict__ root,
                          const void* __restrict__ bias,
                          float* __restrict__ h_new, void* __restrict__ out,
                          const int* __restrict__ flags) {
  const int f32m = flags[0];
  int t = blockIdx.x * 256 + threadIdx.x;
  if (t >= NN * 16) return;
  int n = t >> 4, d = t & 15;
  float acc = aggr[t] + ldf(bias, d, f32m);
  for (int k = 0; k < 16; ++k)
    acc += h_old[n * 16 + k] * ldf(root, (size_t)k * 16 + d, f32m);
  if (h_new) h_new[t] = acc;
  else       stf(out, t, acc, f32m);
}

// --- edge embedding + log_softmax -----------------------------------------
__global__ void k_ee(const void* __restrict__ ea, const void* __restrict__ We,
                     const void* __restrict__ be, void* __restrict__ out,
                     const int* __restrict__ flags) {
  const int f32m = flags[0];
  __shared__ float W[256];
  __shared__ float Bv[16];
  int t = threadIdx.x;
  W[t] = ldf(We, t, f32m);
  if (t < 16) Bv[t] = ldf(be, t, f32m);
  __syncthreads();
  int e = blockIdx.x * 256 + t;
  if (e >= NE) return;
  float v[16];
  if (f32m) {
    const float4* ep = (const float4*)((const float*)ea + (size_t)e * 16);
    float4 r0 = ep[0], r1 = ep[1], r2 = ep[2], r3 = ep[3];
    v[0]=r0.x; v[1]=r0.y; v[2]=r0.z; v[3]=r0.w;
    v[4]=r1.x; v[5]=r1.y; v[6]=r1.z; v[7]=r1.w;
    v[8]=r2.x; v[9]=r2.y; v[10]=r2.z; v[11]=r2.w;
    v[12]=r3.x; v[13]=r3.y; v[14]=r3.z; v[15]=r3.w;
  } else {
    union { uint4 qv[2]; u16 h[16]; } rw;
    const uint4* ep = (const uint4*)((const u16*)ea + (size_t)e * 16);
    rw.qv[0] = ep[0]; rw.qv[1] = ep[1];
#pragma unroll
    for (int k = 0; k < 16; ++k) v[k] = bf2f(rw.h[k]);
  }
  float o[16];
  float mx = 0.f;
#pragma unroll
  for (int d = 0; d < 16; ++d) {
    float acc = Bv[d];
#pragma unroll
    for (int k = 0; k < 16; ++k) acc += v[k] * W[k * 16 + d];
    acc = fmaxf(acc, 0.f);
    o[d] = acc;
    mx = fmaxf(mx, acc);
  }
  float s = 0.f;
#pragma unroll
  for (int d = 0; d < 16; ++d) s += __expf(o[d] - mx);
  float lse = mx + __logf(s);
  const size_t off_ee = 1120000, off_ls = 7520000;
  if (f32m) {
    union { float4 fv; float f[4]; } pe, pl;
    float* oe = (float*)out + off_ee + (size_t)e * 16;
    float* ol = (float*)out + off_ls + (size_t)e * 16;
#pragma unroll
    for (int g = 0; g < 4; ++g) {
#pragma unroll
      for (int d = 0; d < 4; ++d) { pe.f[d] = o[g*4+d]; pl.f[d] = o[g*4+d] - lse; }
      ((float4*)oe)[g] = pe.fv;
      ((float4*)ol)[g] = pl.fv;
    }
  } else {
    union { uint4 qv[2]; u16 h[16]; } pe, pl;
#pragma unroll
    for (int d = 0; d < 16; ++d) {
      pe.h[d] = f2bf(o[d]);
      pl.h[d] = f2bf(o[d] - lse);
    }
    uint4* oe = (uint4*)((u16*)out + off_ee + (size_t)e * 16);
    uint4* ol = (uint4*)((u16*)out + off_ls + (size_t)e * 16);
    oe[0] = pe.qv[0]; oe[1] = pe.qv[1];
    ol[0] = pl.qv[0]; ol[1] = pl.qv[1];
  }
}

// --- edge_index passthrough -----------------------------------------------
__global__ void k_idx(const void* __restrict__ ei, void* __restrict__ out,
                      const int* __restrict__ flags) {
  const int f32m = flags[0], i64m = !flags[1];
  int i = blockIdx.x * 256 + threadIdx.x;
  if (i >= 2 * NE) return;
  float v = i64m ? (float)((const long long*)ei)[i] : (float)((const int*)ei)[i];
  stf(out, (size_t)320000 + i, v, f32m);
}

extern "C" void kernel_launch(void* const* d_in, const int* in_sizes, int n_in,
                              void* d_out, int out_size, void* d_ws, size_t ws_size,
                              hipStream_t stream) {
  const void* x     = d_in[0];
  const void* ei    = d_in[1];
  const void* ea    = d_in[2];
  const void* Wn    = d_in[3];
  const void* bn    = d_in[4];
  const void* We    = d_in[5];
  const void* be    = d_in[6];
  const void* W1    = d_in[7];
  const void* b1    = d_in[8];
  const void* W2    = d_in[9];
  const void* b2    = d_in[10];
  const void* root1 = d_in[11];
  const void* bias1 = d_in[12];
  const void* root2 = d_in[13];
  const void* bias2 = d_in[14];

  char* ws = (char*)d_ws;
  int*   flags = (int*)ws;                              // @0, 16 B
  float* h0   = (float*)(ws + 16);                      // 1,280,000 B
  float* h1   = (float*)(ws + 1280016);                 // 1,280,000 B
  u16*   w2p  = (u16*)(ws + 2560016);                   //   131,072 B
  u16*   w1p  = (u16*)(ws + 2691088);                   //     8,192 B
  // CSR region (@2,699,280):
  float* msg    = (float*)(ws + 2699280);               // 25,600,000 B
  int*   rowptr = (int*)(ws + 28299280);                //     80,016 B
  int*   cursor = (int*)(ws + 28379296);                //     80,000 B
  int*   eidx   = (int*)(ws + 28459296);                //  1,600,000 B
  const size_t need_csr = 30059296;
  // fallback region aliases msg:
  float* aggr = (float*)(ws + 2699280);                 //  1,280,000 B
  const int use_csr = (ws_size >= need_csr) ? 1 : 0;

  hipMemsetAsync(flags, 0, 16, stream);
  k_detect<<<64, 256, 0, stream>>>((const u16*)x, (const int*)ei, flags);
  k_pack_w2<<<32, 256, 0, stream>>>(W2, w2p, flags);
  k_pack_w1<<<2, 256, 0, stream>>>(W1, w1p, flags);
  k_embed<<<1250, 256, 0, stream>>>(x, Wn, bn, h0, flags);

  if (use_csr) {
    hipMemsetAsync(cursor, 0, NN * 4, stream);
    k_count<<<1563, 256, 0, stream>>>(ei, cursor, flags);
    k_scan<<<1, 1024, 0, stream>>>(cursor, rowptr, cursor);
    k_scatter<<<1563, 256, 0, stream>>>(ei, cursor, eidx, flags);

    k_edge<<<512, 256, 0, stream>>>(ea, ei, h0, w2p, w1p, b1, b2, msg, nullptr, flags, 1);
    k_gather<<<1250, 256, 0, stream>>>(msg, rowptr, eidx, h0, root1, bias1, h1, nullptr, flags);
    k_edge<<<512, 256, 0, stream>>>(ea, ei, h1, w2p, w1p, b1, b2, msg, nullptr, flags, 1);
    k_gather<<<1250, 256, 0, stream>>>(msg, rowptr, eidx, h1, root2, bias2, nullptr, d_out, flags);
  } else {
    hipMemsetAsync(aggr, 0, (size_t)NN * 16 * 4, stream);
    k_edge<<<512, 256, 0, stream>>>(ea, ei, h0, w2p, w1p, b1, b2, nullptr, aggr, flags, 0);
    k_combine<<<1250, 256, 0, stream>>>(h0, aggr, root1, bias1, h1, nullptr, flags);
    hipMemsetAsync(aggr, 0, (size_t)NN * 16 * 4, stream);
    k_edge<<<512, 256, 0, stream>>>(ea, ei, h1, w2p, w1p, b1, b2, nullptr, aggr, flags, 0);
    k_combine<<<1250, 256, 0, stream>>>(h1, aggr, root2, bias2, nullptr, d_out, flags);
  }

  k_ee<<<1563, 256, 0, stream>>>(ea, We, be, d_out, flags);
  k_idx<<<3125, 256, 0, stream>>>(ei, d_out, flags);
}

// Round 4
// 615.721 us; speedup vs baseline: 1.5572x; 1.0493x over previous
//
#include <hip/hip_runtime.h>
#include <hip/hip_bf16.h>

// ---------------------------------------------------------------------------
// GNN encoder for MI355X — latency-optimized k_edge (one tile per block).
// R3 profile: all pipes <12%, occupancy 20% -> latency-bound. Fixes: one
// 128-edge tile per block (cross-block overlap), nf transposed for b128
// broadcast reads, ea direct global->A-frag, W1 frags in regs, CSR-permuted
// bf16 msg so k_gather reads contiguously. Dtype-adaptive as before.
// ---------------------------------------------------------------------------

#define NN 20000
#define NE 400000

typedef unsigned short u16;
typedef unsigned int   u32;
typedef __attribute__((ext_vector_type(8))) short short8;
typedef __attribute__((ext_vector_type(4))) float f32x4;

__device__ __forceinline__ float bf2f(u16 h) {
  union { u32 u; float f; } v; v.u = ((u32)h) << 16; return v.f;
}
__device__ __forceinline__ u16 f2bf(float f) {
  union { float f; u32 u; } v; v.f = f;
  return (u16)((v.u + 0x7FFFu + ((v.u >> 16) & 1u)) >> 16);
}
__device__ __forceinline__ float ldf(const void* p, size_t i, int f32m) {
  return f32m ? ((const float*)p)[i] : bf2f(((const u16*)p)[i]);
}
__device__ __forceinline__ int ldi(const void* p, size_t i, int i64m) {
  return i64m ? (int)((const long long*)p)[i] : ((const int*)p)[i];
}
__device__ __forceinline__ void stf(void* p, size_t i, float v, int f32m) {
  if (f32m) ((float*)p)[i] = v; else ((u16*)p)[i] = f2bf(v);
}

// --- dtype detection (flags pre-zeroed by memset) --------------------------
__global__ void k_detect(const u16* __restrict__ x16,
                         const int* __restrict__ ei32, int* __restrict__ flags) {
  int t = blockIdx.x * 256 + threadIdx.x;
  int found_f32 = 0, found_hi = 0;
  for (int i = t; i < NN * 16; i += 64 * 256) {
    u16 v = x16[i];
    if ((v & 0x7F80u) == 0x7F80u) found_f32 = 1;  // Inf/NaN pattern: only f32 halves
  }
  for (int i = t; i < 200000; i += 64 * 256)
    if (ei32[2 * i + 1] != 0) found_hi = 1;
  if (__any(found_f32) && (threadIdx.x & 63) == 0) atomicOr(&flags[0], 1);
  if (__any(found_hi) && (threadIdx.x & 63) == 0) atomicOr(&flags[1], 1);
}

// --- pack W2 [128,512] into MFMA B-fragment order -------------------------
__global__ void k_pack_w2(const void* __restrict__ W2, u16* __restrict__ w2p,
                          const int* __restrict__ flags) {
  const int f32m = flags[0];
  int t = blockIdx.x * 256 + threadIdx.x;          // 32*4*64 = 8192
  if (t >= 32 * 4 * 64) return;
  int lane = t & 63;
  int ks = (t >> 6) & 3;
  int kb = t >> 8;
  int n = lane & 15, q = lane >> 4;
  for (int j = 0; j < 8; ++j) {
    int h = ks * 32 + q * 8 + j;
    w2p[(size_t)t * 8 + j] = f2bf(ldf(W2, (size_t)h * 512 + kb * 16 + n, f32m));
  }
}

// --- pack W1 [16,128] zero-padded to K=32 into B-fragment order -----------
__global__ void k_pack_w1(const void* __restrict__ W1, u16* __restrict__ w1p,
                          const int* __restrict__ flags) {
  const int f32m = flags[0];
  int t = blockIdx.x * 256 + threadIdx.x;          // 8*64 = 512
  if (t >= 8 * 64) return;
  int lane = t & 63;
  int n = t >> 6;
  int col = n * 16 + (lane & 15), q = lane >> 4;
  for (int j = 0; j < 8; ++j) {
    int kk = q * 8 + j;
    w1p[(size_t)t * 8 + j] = (kk < 16) ? f2bf(ldf(W1, (size_t)kk * 128 + col, f32m)) : (u16)0;
  }
}

// --- node embedding: h0 = relu(x @ Wn + bn) -------------------------------
__global__ void k_embed(const void* __restrict__ x, const void* __restrict__ Wn,
                        const void* __restrict__ bn, float* __restrict__ h0,
                        const int* __restrict__ flags) {
  const int f32m = flags[0];
  int t = blockIdx.x * 256 + threadIdx.x;
  if (t >= NN * 16) return;
  int n = t >> 4, d = t & 15;
  float acc = ldf(bn, d, f32m);
  for (int k = 0; k < 16; ++k)
    acc += ldf(x, n * 16 + k, f32m) * ldf(Wn, k * 16 + d, f32m);
  h0[t] = fmaxf(acc, 0.f);
}

// --- CSR build -------------------------------------------------------------
__global__ void k_count(const void* __restrict__ ei, int* __restrict__ cnt,
                        const int* __restrict__ flags) {
  const int i64m = !flags[1];
  int i = blockIdx.x * 256 + threadIdx.x;
  if (i < NE) atomicAdd(&cnt[ldi(ei, NE + i, i64m)], 1);
}

__global__ void k_scan(const int* __restrict__ cnt, int* __restrict__ rowptr,
                       int* __restrict__ cursor) {
  __shared__ int part[1024];
  int t = threadIdx.x;
  int base = t * 20;                               // 1024*20 = 20480 >= NN
  int s = 0;
  for (int j = 0; j < 20; ++j) { int idx = base + j; if (idx < NN) s += cnt[idx]; }
  part[t] = s;
  __syncthreads();
  for (int off = 1; off < 1024; off <<= 1) {
    int v = (t >= off) ? part[t - off] : 0;
    __syncthreads();
    part[t] += v;
    __syncthreads();
  }
  int run = t ? part[t - 1] : 0;
  for (int j = 0; j < 20; ++j) {
    int idx = base + j;
    if (idx < NN) {
      int c = cnt[idx];                            // read BEFORE cursor aliasing write
      rowptr[idx] = run; cursor[idx] = run; run += c;
    }
  }
  if (t == 1023) rowptr[NN] = part[1023];
}

// stores inv[e] = CSR slot of edge e (msg written permuted, gather contiguous)
__global__ void k_scatter(const void* __restrict__ ei, int* __restrict__ cursor,
                          int* __restrict__ inv, const int* __restrict__ flags) {
  const int i64m = !flags[1];
  int i = blockIdx.x * 256 + threadIdx.x;
  if (i >= NE) return;
  int d = ldi(ei, NE + i, i64m);
  int pos = atomicAdd(&cursor[d], 1);
  inv[i] = pos;
}

// --- fused edge kernel: one 128-edge tile per block -----------------------
__launch_bounds__(256, 2)
__global__ void k_edge(const void* __restrict__ ea, const void* __restrict__ ei,
                       const float* __restrict__ hprev,
                       const u16* __restrict__ w2p, const u16* __restrict__ w1p,
                       const void* __restrict__ b1, const void* __restrict__ b2,
                       u16* __restrict__ msg16, float* __restrict__ aggr,
                       const int* __restrict__ inv,
                       const int* __restrict__ flags, int use_csr) {
  __shared__ u16   a2_lds[128 * 136];   // 34816 B; word-stride ≡ 4 mod 32
  __shared__ float nfT[32 * 132];       // 16896 B; nfT[kb][edge], b128 broadcast
  __shared__ float msg_lds[128 * 17];   //  8704 B
  __shared__ float b1_lds[128];
  __shared__ int   dst_lds[128];

  const int f32m = flags[0], i64m = !flags[1];
  const int t = threadIdx.x;
  const int lane = t & 63, w = t >> 6;
  const int q = lane >> 4, l16 = lane & 15;
  const int e0 = blockIdx.x * 128;

  // Register preloads (L2-resident; scheduler hoists, waits land late)
  short8 B[8][4];
  {
    const short8* w2pf = (const short8*)w2p;
#pragma unroll
    for (int i = 0; i < 8; ++i)
#pragma unroll
      for (int ks = 0; ks < 4; ++ks)
        B[i][ks] = w2pf[((w * 8 + i) * 4 + ks) * 64 + lane];
  }
  float b2v[8];
#pragma unroll
  for (int i = 0; i < 8; ++i) b2v[i] = ldf(b2, (w * 8 + i) * 16 + l16, f32m);
  short8 W1f[8];
  {
    const short8* w1pf = (const short8*)w1p;
#pragma unroll
    for (int n = 0; n < 8; ++n) W1f[n] = w1pf[n * 64 + lane];
  }
  if (t < 128) b1_lds[t] = ldf(b1, t, f32m);

  {  // phase 0: gather nf (transposed), dst slot, zero msg
    int e = t >> 1, hh = t & 1;               // hh=0 -> dst, hh=1 -> src
    int node = hh ? ldi(ei, e0 + e, i64m) : ldi(ei, NE + e0 + e, i64m);
    const float4* hp = (const float4*)(hprev + (size_t)node * 16);
    float4 h0v = hp[0], h1v = hp[1], h2v = hp[2], h3v = hp[3];
    float* col = nfT + (size_t)(hh * 16) * 132 + e;
    col[0 * 132] = h0v.x; col[1 * 132] = h0v.y; col[2 * 132] = h0v.z; col[3 * 132] = h0v.w;
    col[4 * 132] = h1v.x; col[5 * 132] = h1v.y; col[6 * 132] = h1v.z; col[7 * 132] = h1v.w;
    col[8 * 132] = h2v.x; col[9 * 132] = h2v.y; col[10 * 132] = h2v.z; col[11 * 132] = h2v.w;
    col[12 * 132] = h3v.x; col[13 * 132] = h3v.y; col[14 * 132] = h3v.z; col[15 * 132] = h3v.w;
    if (!hh) {
      if (use_csr) dst_lds[e] = inv[e0 + e];
      else         dst_lds[e] = node;
    }
    float* mz = msg_lds + e * 17 + hh * 8;
#pragma unroll
    for (int k2 = 0; k2 < 8; ++k2) mz[k2] = 0.f;
  }
  __syncthreads();

  // phase 1: A2 = relu(ea@W1+b1); A-frags straight from global (q>=2 = K-pad 0)
#pragma unroll
  for (int mm = 0; mm < 2; ++mm) {
    int m = w * 2 + mm;
    union { short8 s; u16 h[8]; } ua;
    if (q < 2) {
      if (f32m) {
        const float* er = (const float*)ea + ((size_t)(e0 + m * 16 + l16) * 16 + q * 8);
        float4 f0 = *(const float4*)er;
        float4 f1 = *(const float4*)(er + 4);
        ua.h[0] = f2bf(f0.x); ua.h[1] = f2bf(f0.y); ua.h[2] = f2bf(f0.z); ua.h[3] = f2bf(f0.w);
        ua.h[4] = f2bf(f1.x); ua.h[5] = f2bf(f1.y); ua.h[6] = f2bf(f1.z); ua.h[7] = f2bf(f1.w);
      } else {
        ua.s = *(const short8*)((const u16*)ea + ((size_t)(e0 + m * 16 + l16) * 16 + q * 8));
      }
    } else {
#pragma unroll
      for (int j = 0; j < 8; ++j) ua.h[j] = 0;
    }
    short8 A = ua.s;
#pragma unroll
    for (int n = 0; n < 8; ++n) {
      f32x4 c = {0.f, 0.f, 0.f, 0.f};
      c = __builtin_amdgcn_mfma_f32_16x16x32_bf16(A, W1f[n], c, 0, 0, 0);
      float bb = b1_lds[n * 16 + l16];
#pragma unroll
      for (int r = 0; r < 4; ++r)
        a2_lds[(m * 16 + q * 4 + r) * 136 + n * 16 + l16] =
            f2bf(fmaxf(c[r] + bb, 0.f));
    }
  }
  __syncthreads();

  // phase 2: msg = sum_kb nf[:,kb]*(A2@W2_kb + b2_kb); waves split kb space
#pragma unroll 1
  for (int mi = 0; mi < 8; ++mi) {
    int m = (mi + w * 2) & 7;  // stagger to decorrelate LDS atomics
    const short8* ap = (const short8*)&a2_lds[(m * 16 + l16) * 136 + q * 8];
    short8 A0 = ap[0], A1 = ap[4], A2f = ap[8], A3 = ap[12];
    float mr0 = 0.f, mr1 = 0.f, mr2 = 0.f, mr3 = 0.f;
#pragma unroll
    for (int i = 0; i < 8; ++i) {
      f32x4 c = {b2v[i], b2v[i], b2v[i], b2v[i]};  // b2 rides in C-operand
      c = __builtin_amdgcn_mfma_f32_16x16x32_bf16(A0, B[i][0], c, 0, 0, 0);
      c = __builtin_amdgcn_mfma_f32_16x16x32_bf16(A1, B[i][1], c, 0, 0, 0);
      c = __builtin_amdgcn_mfma_f32_16x16x32_bf16(A2f, B[i][2], c, 0, 0, 0);
      c = __builtin_amdgcn_mfma_f32_16x16x32_bf16(A3, B[i][3], c, 0, 0, 0);
      int kb = w * 8 + i;
      f32x4 nf4 = *(const f32x4*)&nfT[(size_t)kb * 132 + m * 16 + q * 4];  // broadcast b128
      mr0 += nf4[0] * c[0];
      mr1 += nf4[1] * c[1];
      mr2 += nf4[2] * c[2];
      mr3 += nf4[3] * c[3];
    }
    int eb = (m * 16 + q * 4) * 17 + l16;
    atomicAdd(&msg_lds[eb + 0 * 17], mr0);
    atomicAdd(&msg_lds[eb + 1 * 17], mr1);
    atomicAdd(&msg_lds[eb + 2 * 17], mr2);
    atomicAdd(&msg_lds[eb + 3 * 17], mr3);
  }
  __syncthreads();

  {  // epilogue
    int e = t >> 1, dh = t & 1;
    const float* mp = msg_lds + e * 17 + dh * 8;
    if (use_csr) {  // bf16 msg at CSR slot -> k_gather reads contiguously
      int pos = dst_lds[e];
      union { uint4 qv; u16 h[8]; } pk;
#pragma unroll
      for (int dd = 0; dd < 8; ++dd) pk.h[dd] = f2bf(mp[dd]);
      *(uint4*)(msg16 + (size_t)pos * 16 + dh * 8) = pk.qv;
    } else {        // fallback: scatter atomics to aggr[dst]
      int dnode = dst_lds[e];
      float* ap2 = aggr + (size_t)dnode * 16 + dh * 8;
#pragma unroll
      for (int dd = 0; dd < 8; ++dd) atomicAdd(ap2 + dd, mp[dd]);
    }
  }
}

// --- gather + combine: h_new = csr_sum(msg) + h_old @ root + bias ---------
__global__ void k_gather(const u16* __restrict__ msg16,
                         const int* __restrict__ rowptr,
                         const float* __restrict__ h_old,
                         const void* __restrict__ root,
                         const void* __restrict__ bias,
                         float* __restrict__ h_new, void* __restrict__ out,
                         const int* __restrict__ flags) {
  const int f32m = flags[0];
  __shared__ float R[256];
  __shared__ float Bv[16];
  int tt = threadIdx.x;
  R[tt] = ldf(root, tt, f32m);
  if (tt < 16) Bv[tt] = ldf(bias, tt, f32m);
  __syncthreads();
  int t = blockIdx.x * 256 + tt;
  if (t >= NN * 16) return;
  int n = t >> 4, d = t & 15;
  float acc = Bv[d];
#pragma unroll
  for (int k = 0; k < 16; ++k) acc += h_old[n * 16 + k] * R[k * 16 + d];
  int beg = rowptr[n], end = rowptr[n + 1];
  for (int i = beg; i < end; ++i)          // contiguous bf16 rows
    acc += bf2f(msg16[(size_t)i * 16 + d]);
  if (h_new) h_new[t] = acc;
  else       stf(out, t, acc, f32m);
}

// --- fallback combine (non-CSR path) --------------------------------------
__global__ void k_combine(const float* __restrict__ h_old,
                          const float* __restrict__ aggr,
                          const void* __restrict__ root,
                          const void* __restrict__ bias,
                          float* __restrict__ h_new, void* __restrict__ out,
                          const int* __restrict__ flags) {
  const int f32m = flags[0];
  int t = blockIdx.x * 256 + threadIdx.x;
  if (t >= NN * 16) return;
  int n = t >> 4, d = t & 15;
  float acc = aggr[t] + ldf(bias, d, f32m);
  for (int k = 0; k < 16; ++k)
    acc += h_old[n * 16 + k] * ldf(root, (size_t)k * 16 + d, f32m);
  if (h_new) h_new[t] = acc;
  else       stf(out, t, acc, f32m);
}

// --- edge embedding + log_softmax -----------------------------------------
__global__ void k_ee(const void* __restrict__ ea, const void* __restrict__ We,
                     const void* __restrict__ be, void* __restrict__ out,
                     const int* __restrict__ flags) {
  const int f32m = flags[0];
  __shared__ float W[256];
  __shared__ float Bv[16];
  int t = threadIdx.x;
  W[t] = ldf(We, t, f32m);
  if (t < 16) Bv[t] = ldf(be, t, f32m);
  __syncthreads();
  int e = blockIdx.x * 256 + t;
  if (e >= NE) return;
  float v[16];
  if (f32m) {
    const float4* ep = (const float4*)((const float*)ea + (size_t)e * 16);
    float4 r0 = ep[0], r1 = ep[1], r2 = ep[2], r3 = ep[3];
    v[0]=r0.x; v[1]=r0.y; v[2]=r0.z; v[3]=r0.w;
    v[4]=r1.x; v[5]=r1.y; v[6]=r1.z; v[7]=r1.w;
    v[8]=r2.x; v[9]=r2.y; v[10]=r2.z; v[11]=r2.w;
    v[12]=r3.x; v[13]=r3.y; v[14]=r3.z; v[15]=r3.w;
  } else {
    union { uint4 qv[2]; u16 h[16]; } rw;
    const uint4* ep = (const uint4*)((const u16*)ea + (size_t)e * 16);
    rw.qv[0] = ep[0]; rw.qv[1] = ep[1];
#pragma unroll
    for (int k = 0; k < 16; ++k) v[k] = bf2f(rw.h[k]);
  }
  float o[16];
  float mx = 0.f;
#pragma unroll
  for (int d = 0; d < 16; ++d) {
    float acc = Bv[d];
#pragma unroll
    for (int k = 0; k < 16; ++k) acc += v[k] * W[k * 16 + d];
    acc = fmaxf(acc, 0.f);
    o[d] = acc;
    mx = fmaxf(mx, acc);
  }
  float s = 0.f;
#pragma unroll
  for (int d = 0; d < 16; ++d) s += __expf(o[d] - mx);
  float lse = mx + __logf(s);
  const size_t off_ee = 1120000, off_ls = 7520000;
  if (f32m) {
    union { float4 fv; float f[4]; } pe, pl;
    float* oe = (float*)out + off_ee + (size_t)e * 16;
    float* ol = (float*)out + off_ls + (size_t)e * 16;
#pragma unroll
    for (int g = 0; g < 4; ++g) {
#pragma unroll
      for (int d = 0; d < 4; ++d) { pe.f[d] = o[g*4+d]; pl.f[d] = o[g*4+d] - lse; }
      ((float4*)oe)[g] = pe.fv;
      ((float4*)ol)[g] = pl.fv;
    }
  } else {
    union { uint4 qv[2]; u16 h[16]; } pe, pl;
#pragma unroll
    for (int d = 0; d < 16; ++d) {
      pe.h[d] = f2bf(o[d]);
      pl.h[d] = f2bf(o[d] - lse);
    }
    uint4* oe = (uint4*)((u16*)out + off_ee + (size_t)e * 16);
    uint4* ol = (uint4*)((u16*)out + off_ls + (size_t)e * 16);
    oe[0] = pe.qv[0]; oe[1] = pe.qv[1];
    ol[0] = pl.qv[0]; ol[1] = pl.qv[1];
  }
}

// --- edge_index passthrough -----------------------------------------------
__global__ void k_idx(const void* __restrict__ ei, void* __restrict__ out,
                      const int* __restrict__ flags) {
  const int f32m = flags[0], i64m = !flags[1];
  int i = blockIdx.x * 256 + threadIdx.x;
  if (i >= 2 * NE) return;
  float v = i64m ? (float)((const long long*)ei)[i] : (float)((const int*)ei)[i];
  stf(out, (size_t)320000 + i, v, f32m);
}

extern "C" void kernel_launch(void* const* d_in, const int* in_sizes, int n_in,
                              void* d_out, int out_size, void* d_ws, size_t ws_size,
                              hipStream_t stream) {
  const void* x     = d_in[0];
  const void* ei    = d_in[1];
  const void* ea    = d_in[2];
  const void* Wn    = d_in[3];
  const void* bn    = d_in[4];
  const void* We    = d_in[5];
  const void* be    = d_in[6];
  const void* W1    = d_in[7];
  const void* b1    = d_in[8];
  const void* W2    = d_in[9];
  const void* b2    = d_in[10];
  const void* root1 = d_in[11];
  const void* bias1 = d_in[12];
  const void* root2 = d_in[13];
  const void* bias2 = d_in[14];

  char* ws = (char*)d_ws;
  int*   flags = (int*)ws;                              // @0, 16 B
  float* h0     = (float*)(ws + 16);                    // 1,280,000 B
  float* h1     = (float*)(ws + 1280016);               // 1,280,000 B
  u16*   w2p    = (u16*)(ws + 2560016);                 //   131,072 B
  u16*   w1p    = (u16*)(ws + 2691088);                 //     8,192 B
  u16*   msg16  = (u16*)(ws + 2699280);                 // 12,800,000 B
  int*   rowptr = (int*)(ws + 15499280);                //     80,016 B
  int*   cursor = (int*)(ws + 15579296);                //     80,000 B
  int*   inv    = (int*)(ws + 15659296);                //  1,600,000 B
  const size_t need_csr = 17259296;
  float* aggr = (float*)(ws + 2699280);                 // fallback aliases msg16
  const int use_csr = (ws_size >= need_csr) ? 1 : 0;

  hipMemsetAsync(flags, 0, 16, stream);
  k_detect<<<64, 256, 0, stream>>>((const u16*)x, (const int*)ei, flags);
  k_pack_w2<<<32, 256, 0, stream>>>(W2, w2p, flags);
  k_pack_w1<<<2, 256, 0, stream>>>(W1, w1p, flags);
  k_embed<<<1250, 256, 0, stream>>>(x, Wn, bn, h0, flags);

  if (use_csr) {
    hipMemsetAsync(cursor, 0, NN * 4, stream);
    k_count<<<1563, 256, 0, stream>>>(ei, cursor, flags);
    k_scan<<<1, 1024, 0, stream>>>(cursor, rowptr, cursor);
    k_scatter<<<1563, 256, 0, stream>>>(ei, cursor, inv, flags);

    k_edge<<<3125, 256, 0, stream>>>(ea, ei, h0, w2p, w1p, b1, b2, msg16, nullptr, inv, flags, 1);
    k_gather<<<1250, 256, 0, stream>>>(msg16, rowptr, h0, root1, bias1, h1, nullptr, flags);
    k_edge<<<3125, 256, 0, stream>>>(ea, ei, h1, w2p, w1p, b1, b2, msg16, nullptr, inv, flags, 1);
    k_gather<<<1250, 256, 0, stream>>>(msg16, rowptr, h1, root2, bias2, nullptr, d_out, flags);
  } else {
    hipMemsetAsync(aggr, 0, (size_t)NN * 16 * 4, stream);
    k_edge<<<3125, 256, 0, stream>>>(ea, ei, h0, w2p, w1p, b1, b2, nullptr, aggr, nullptr, flags, 0);
    k_combine<<<1250, 256, 0, stream>>>(h0, aggr, root1, bias1, h1, nullptr, flags);
    hipMemsetAsync(aggr, 0, (size_t)NN * 16 * 4, stream);
    k_edge<<<3125, 256, 0, stream>>>(ea, ei, h1, w2p, w1p, b1, b2, nullptr, aggr, nullptr, flags, 0);
    k_combine<<<1250, 256, 0, stream>>>(h1, aggr, root2, bias2, nullptr, d_out, flags);
  }

  k_ee<<<1563, 256, 0, stream>>>(ea, We, be, d_out, flags);
  k_idx<<<3125, 256, 0, stream>>>(ei, d_out, flags);
}